// Round 5
// baseline (665.598 us; speedup 1.0000x reference)
//
#include <hip/hip_runtime.h>

typedef _Float16 half8 __attribute__((ext_vector_type(8)));
typedef float floatx4 __attribute__((ext_vector_type(4)));

#define Bsz 512
#define Tsz 168
#define Fsz 16
#define Hsz 256
#define KTILES 9      // K = 288 = 9 * 32  (256 h + 16 x + 16 zero pad)
#define LDS_K 296     // padded LDS row stride in halves

// workspace layout (bytes, all 16B aligned)
#define WSW_OFF   0          // swizzled [w_hh|w_ih|0] f16 frags: 64nt*9kt*64lane*16B = 589824
#define BIAS_OFF  589824     // reordered (b_ih+b_hh) fp32: 1024*4 = 4096
#define FC1_OFF   593920     // fc1 frags: 8nt*8kt*64*16B = 65536
#define FC2_OFF   659456     // fc2 frags: 4nt*4kt*64*16B = 16384
#define HH_OFF    675840     // h history f16 [B][T][H]: 512*168*256*2 = 44040192
#define FLG_OFF   (HH_OFF + 44040192)   // step flags: 168*64*4 = 43008 B

// ---------------- prep: swizzle recurrent weights into MFMA B-frag order ----
// nt -> J = nt>>2 (j-block), g = nt&3 (torch gate i,f,g,o)
// B-frag: lane = n_in + 16*kg holds B[k = kt*32 + kg*8 + e][n], e=0..7
__global__ void k_swz_whh(const float* __restrict__ w_hh,
                          const float* __restrict__ w_ih,
                          _Float16* __restrict__ wsw) {
    int tile = blockIdx.x;            // nt*9 + kt, 576 tiles
    int nt = tile / KTILES, kt = tile - nt * KTILES;
    int lane = threadIdx.x;           // 64
    int n_in = lane & 15, kg = lane >> 4;
    int J = nt >> 2, g = nt & 3;
    int n_orig = g * 256 + J * 16 + n_in;
    half8 v;
#pragma unroll
    for (int e = 0; e < 8; ++e) {
        int k = kt * 32 + kg * 8 + e;
        float f;
        if (k < 256)      f = w_hh[n_orig * 256 + k];
        else if (k < 272) f = w_ih[n_orig * 16 + (k - 256)];
        else              f = 0.0f;
        v[e] = (_Float16)f;
    }
    ((half8*)wsw)[tile * 64 + lane] = v;
}

__global__ void k_bias(const float* __restrict__ b_ih,
                       const float* __restrict__ b_hh,
                       float* __restrict__ bias) {
    int id = blockIdx.x * 256 + threadIdx.x;   // 1024
    int nt = id >> 4, n = id & 15;
    int J = nt >> 2, g = nt & 3;
    int n_orig = g * 256 + J * 16 + n;
    bias[id] = b_ih[n_orig] + b_hh[n_orig];
}

__global__ void k_swz_fc(const float* __restrict__ w, _Float16* __restrict__ dst,
                         int ktiles, int K) {
    int tile = blockIdx.x;
    int nt = tile / ktiles, kt = tile - nt * ktiles;
    int lane = threadIdx.x;
    int n_in = lane & 15, kg = lane >> 4;
    int n_orig = nt * 16 + n_in;
    half8 v;
#pragma unroll
    for (int e = 0; e < 8; ++e) {
        int k = kt * 32 + kg * 8 + e;
        v[e] = (_Float16)w[n_orig * K + k];
    }
    ((half8*)dst)[tile * 64 + lane] = v;
}

// ---------------- recurrent LSTM v5: 64 WGs = 32 bb x 2 halves -------------
// WG (bb, p): M=16 rows, gates j in [p*128, p*128+128). Wave w owns J-block
// J=p*8+w, all 4 gates. R4 lesson: "+v" anchors don't stop the allocator
// SPILLING 144 VGPRs of weights (VGPR_Count stayed 112, dur unchanged).
// v5: pin 32 frags (kt=0..7) in AGPRs via "+a" anchors -- MFMA reads B
// directly from AGPRs (ISA 10), and the AGPR file has zero competing
// pressure. kt=8 (x|pad columns, 4 frags) streamed from L2 per step.
// Budget: 128 AGPR + ~115 VGPR < 256 combined @ 2 waves/SIMD.
__global__ __attribute__((amdgpu_flat_work_group_size(512, 512),
                          amdgpu_waves_per_eu(2, 2)))
void k_lstm5(
    const float* __restrict__ x, const _Float16* __restrict__ wsw,
    const float* __restrict__ bias, unsigned long long* __restrict__ hh64,
    unsigned* __restrict__ flags) {
    __shared__ _Float16 h_lds[16][LDS_K];   // [m][k]: h(0..255) | x(256..271) | 0(272..287)

    const int tid = threadIdx.x;
    const int wave = tid >> 6, lane = tid & 63;
    const int n_in = lane & 15, quad = lane >> 4;
    const int bb = blockIdx.x >> 1, p = blockIdx.x & 1;
    const int b0 = bb * 16;
    const int J = p * 8 + wave;            // this wave's j-block

    // ---- load + PIN 32 B-fragments (4 gates x kt=0..7) into AGPRs ----
    half8 wpin[4][8];
    float bs[4];
#pragma unroll
    for (int g = 0; g < 4; ++g) {
        const int nt = J * 4 + g;
        bs[g] = bias[nt * 16 + n_in];
#pragma unroll
        for (int kt = 0; kt < 8; ++kt)
            wpin[g][kt] = ((const half8*)wsw)[(nt * KTILES + kt) * 64 + lane];
    }
#pragma unroll
    for (int g = 0; g < 4; ++g)
#pragma unroll
        for (int kt = 0; kt < 8; ++kt) {
            floatx4 tmp = __builtin_bit_cast(floatx4, wpin[g][kt]);
            asm volatile("" : "+a"(tmp));            // force AGPR residency
            wpin[g][kt] = __builtin_bit_cast(half8, tmp);
        }

    // zero h0 + pad, stage x_0
    for (int i = tid; i < 16 * LDS_K; i += 512)
        ((_Float16*)h_lds)[i] = (_Float16)0.0f;
    __syncthreads();
    if (tid < 256) {
        int m = tid >> 4, f = tid & 15;
        h_lds[m][Hsz + f] = (_Float16)x[((b0 + m) * Tsz + 0) * Fsz + f];
    }
    __syncthreads();

    float c_st[4] = {0.f, 0.f, 0.f, 0.f};   // lane owns (m=quad*4+r, j=J*16+n_in)
    const int gm = tid >> 5, gc = tid & 31; // pack/gather: row m, 8B chunk
    const half8* wf = (const half8*)wsw;

    for (int t = 0; t < Tsz; ++t) {
        // ---- stream kt=8 B-frags (x|pad columns) from L2; A-frags from LDS ----
        half8 wx[4];
#pragma unroll
        for (int g = 0; g < 4; ++g)
            wx[g] = wf[((J * 4 + g) * KTILES + 8) * 64 + lane];

        half8 afr[KTILES];
#pragma unroll
        for (int kt = 0; kt < KTILES; ++kt)
            afr[kt] = *(const half8*)&h_lds[n_in][kt * 32 + quad * 8];

        floatx4 acc[4];
#pragma unroll
        for (int g = 0; g < 4; ++g) acc[g] = (floatx4){0.f, 0.f, 0.f, 0.f};
#pragma unroll
        for (int g = 0; g < 4; ++g) {
#pragma unroll
            for (int kt = 0; kt < 8; ++kt)
                acc[g] = __builtin_amdgcn_mfma_f32_16x16x32_f16(afr[kt], wpin[g][kt], acc[g], 0, 0, 0);
            acc[g] = __builtin_amdgcn_mfma_f32_16x16x32_f16(afr[8], wx[g], acc[g], 0, 0, 0);
        }

        // ---- in-wave cell update: lane owns 4 (m,j) pairs ----
        _Float16 hv[4];
#pragma unroll
        for (int r = 0; r < 4; ++r) {
            float ig = acc[0][r] + bs[0];
            float fg = acc[1][r] + bs[1];
            float gg = acc[2][r] + bs[2];
            float og = acc[3][r] + bs[3];
            float si = 1.0f / (1.0f + __expf(-ig));
            float sf = 1.0f / (1.0f + __expf(-fg));
            float tg = 1.0f - 2.0f / (__expf(2.0f * gg) + 1.0f);
            float so = 1.0f / (1.0f + __expf(-og));
            float c = sf * c_st[r] + si * tg;
            c_st[r] = c;
            float th = 1.0f - 2.0f / (__expf(2.0f * c) + 1.0f);
            hv[r] = (_Float16)(so * th);
        }

        __syncthreads();   // A: all waves' A-frag reads done -> safe to overwrite h
#pragma unroll
        for (int r = 0; r < 4; ++r)
            h_lds[quad * 4 + r][J * 16 + n_in] = hv[r];
        __syncthreads();   // B: own half of h_{t+1} complete in LDS

        // ---- publish own half to hh (LLC, relaxed agent) ----
        unsigned long long pk;
        __builtin_memcpy(&pk, &h_lds[gm][p * 128 + gc * 4], 8);
        __hip_atomic_store(hh64 + ((size_t)(b0 + gm) * Tsz + t) * 64 + p * 32 + gc,
                           pk, __ATOMIC_RELAXED, __HIP_MEMORY_SCOPE_AGENT);

        // prefetch x_{t+1} while stores drain
        float xr = 0.0f;
        if (t + 1 < Tsz && tid < 256)
            xr = x[((b0 + (tid >> 4)) * Tsz + (t + 1)) * Fsz + (tid & 15)];

        __syncthreads();         // C: drains vmcnt -> all 512 threads' stores acked

        if (t + 1 < Tsz) {
            if (tid == 0) {
                __hip_atomic_store(&flags[t * 64 + bb * 2 + p], 1u,
                                   __ATOMIC_RELAXED, __HIP_MEMORY_SCOPE_AGENT);
                // single-thread poll (relaxed: no cache maintenance per spin)
                while (__hip_atomic_load(&flags[t * 64 + bb * 2 + (1 - p)],
                                         __ATOMIC_RELAXED, __HIP_MEMORY_SCOPE_AGENT) == 0u)
                    ;
            }
            __syncthreads();     // F: partner's data globally visible

            // gather partner half (4 KB) into LDS; stage x_{t+1}
            unsigned long long pv = __hip_atomic_load(
                hh64 + ((size_t)(b0 + gm) * Tsz + t) * 64 + (1 - p) * 32 + gc,
                __ATOMIC_RELAXED, __HIP_MEMORY_SCOPE_AGENT);
            __builtin_memcpy(&h_lds[gm][(1 - p) * 128 + gc * 4], &pv, 8);
            if (tid < 256)
                h_lds[tid >> 4][Hsz + (tid & 15)] = (_Float16)xr;
            __syncthreads();     // E: full h_{t+1} + x_{t+1} staged
        }
    }
}

// ---------------- MLP head: 64 tokens/WG (4 waves x 16), MFMA f16 ----------
__global__ __launch_bounds__(256) void k_mlp(
    const _Float16* __restrict__ hh, const _Float16* __restrict__ w1f,
    const _Float16* __restrict__ w2f, const float* __restrict__ b1,
    const float* __restrict__ b2, const float* __restrict__ w3,
    const float* __restrict__ b3, float* __restrict__ out) {
    __shared__ _Float16 st1[4][16][136];
    __shared__ _Float16 st2[4][16][72];

    const int tid = threadIdx.x;
    const int wave = tid >> 6, lane = tid & 63;
    const int n_in = lane & 15, quad = lane >> 4;
    const int tok0 = blockIdx.x * 64 + wave * 16;

    half8 afr[8];
#pragma unroll
    for (int kt = 0; kt < 8; ++kt)
        afr[kt] = *(const half8*)&hh[(size_t)(tok0 + n_in) * 256 + kt * 32 + quad * 8];
    const half8* w1 = (const half8*)w1f;
#pragma unroll
    for (int nt = 0; nt < 8; ++nt) {
        floatx4 a = (floatx4){0.f, 0.f, 0.f, 0.f};
#pragma unroll
        for (int kt = 0; kt < 8; ++kt)
            a = __builtin_amdgcn_mfma_f32_16x16x32_f16(afr[kt], w1[(nt * 8 + kt) * 64 + lane], a, 0, 0, 0);
        float bb = b1[nt * 16 + n_in];
#pragma unroll
        for (int r = 0; r < 4; ++r) {
            float v = a[r] + bb;
            st1[wave][quad * 4 + r][nt * 16 + n_in] = (_Float16)(v > 0.f ? v : 0.f);
        }
    }
    __syncthreads();

    half8 a2[4];
#pragma unroll
    for (int kt = 0; kt < 4; ++kt)
        a2[kt] = *(const half8*)&st1[wave][n_in][kt * 32 + quad * 8];
    const half8* w2 = (const half8*)w2f;
#pragma unroll
    for (int nt = 0; nt < 4; ++nt) {
        floatx4 a = (floatx4){0.f, 0.f, 0.f, 0.f};
#pragma unroll
        for (int kt = 0; kt < 4; ++kt)
            a = __builtin_amdgcn_mfma_f32_16x16x32_f16(a2[kt], w2[(nt * 4 + kt) * 64 + lane], a, 0, 0, 0);
        float bb = b2[nt * 16 + n_in];
#pragma unroll
        for (int r = 0; r < 4; ++r) {
            float v = a[r] + bb;
            st2[wave][quad * 4 + r][nt * 16 + n_in] = (_Float16)(v > 0.f ? v : 0.f);
        }
    }
    __syncthreads();

    float p = 0.0f;
#pragma unroll
    for (int e = 0; e < 16; ++e)
        p += (float)st2[wave][n_in][quad * 16 + e] * w3[quad * 16 + e];
    p += __shfl_down(p, 32);
    p += __shfl_down(p, 16);
    if (quad == 0) out[tok0 + n_in] = p + b3[0];
}

extern "C" void kernel_launch(void* const* d_in, const int* in_sizes, int n_in,
                              void* d_out, int out_size, void* d_ws, size_t ws_size,
                              hipStream_t stream) {
    const float* x     = (const float*)d_in[0];
    const float* w_ih  = (const float*)d_in[1];
    const float* w_hh  = (const float*)d_in[2];
    const float* b_ih  = (const float*)d_in[3];
    const float* b_hh  = (const float*)d_in[4];
    const float* fc1_w = (const float*)d_in[5];
    const float* fc1_b = (const float*)d_in[6];
    const float* fc2_w = (const float*)d_in[7];
    const float* fc2_b = (const float*)d_in[8];
    const float* fc3_w = (const float*)d_in[9];
    const float* fc3_b = (const float*)d_in[10];

    char* ws = (char*)d_ws;
    _Float16* wsw  = (_Float16*)(ws + WSW_OFF);
    float*    bias = (float*)(ws + BIAS_OFF);
    _Float16* w1f  = (_Float16*)(ws + FC1_OFF);
    _Float16* w2f  = (_Float16*)(ws + FC2_OFF);
    _Float16* hhist= (_Float16*)(ws + HH_OFF);
    unsigned* flg  = (unsigned*)(ws + FLG_OFF);

    hipMemsetAsync(flg, 0, Tsz * 64 * sizeof(unsigned), stream);
    k_swz_whh<<<576, 64, 0, stream>>>(w_hh, w_ih, wsw);
    k_bias<<<4, 256, 0, stream>>>(b_ih, b_hh, bias);
    k_swz_fc<<<64, 64, 0, stream>>>(fc1_w, w1f, 8, 256);
    k_swz_fc<<<16, 64, 0, stream>>>(fc2_w, w2f, 4, 128);
    k_lstm5<<<64, 512, 0, stream>>>(x, wsw, bias,
                                    (unsigned long long*)hhist, flg);
    k_mlp<<<Bsz * Tsz / 64, 256, 0, stream>>>(hhist, w1f, w2f, fc1_b, fc2_b,
                                              fc3_w, fc3_b, (float*)d_out);
}

// Round 6
// 626.418 us; speedup vs baseline: 1.0625x; 1.0625x over previous
//
#include <hip/hip_runtime.h>

typedef _Float16 half8 __attribute__((ext_vector_type(8)));
typedef float floatx4 __attribute__((ext_vector_type(4)));

#define Bsz 512
#define Tsz 168
#define Fsz 16
#define Hsz 256
#define KTILES 9      // K = 288 = 9 * 32  (256 h + 16 x + 16 zero pad)
#define LDS_K 296     // padded LDS row stride in halves

// workspace layout (bytes, all 16B aligned)
#define WSW_OFF   0          // swizzled [w_hh|w_ih|0] f16 frags: 64nt*9kt*64lane*16B = 589824
#define BIAS_OFF  589824     // reordered (b_ih+b_hh) fp32: 1024*4 = 4096
#define FC1_OFF   593920     // fc1 frags: 8nt*8kt*64*16B = 65536
#define FC2_OFF   659456     // fc2 frags: 4nt*4kt*64*16B = 16384
#define HH_OFF    675840     // h history f16 [B][T][H]: 512*168*256*2 = 44040192
#define CNT_OFF   (HH_OFF + 44040192)   // step counters: 168*32*4 = 21504 B

// ---------------- prep: swizzle recurrent weights into MFMA B-frag order ----
// nt -> J = nt>>2 (j-block), g = nt&3 (torch gate i,f,g,o)
// B-frag: lane = n_in + 16*kg holds B[k = kt*32 + kg*8 + e][n], e=0..7
__global__ void k_swz_whh(const float* __restrict__ w_hh,
                          const float* __restrict__ w_ih,
                          _Float16* __restrict__ wsw) {
    int tile = blockIdx.x;            // nt*9 + kt, 576 tiles
    int nt = tile / KTILES, kt = tile - nt * KTILES;
    int lane = threadIdx.x;           // 64
    int n_in = lane & 15, kg = lane >> 4;
    int J = nt >> 2, g = nt & 3;
    int n_orig = g * 256 + J * 16 + n_in;
    half8 v;
#pragma unroll
    for (int e = 0; e < 8; ++e) {
        int k = kt * 32 + kg * 8 + e;
        float f;
        if (k < 256)      f = w_hh[n_orig * 256 + k];
        else if (k < 272) f = w_ih[n_orig * 16 + (k - 256)];
        else              f = 0.0f;
        v[e] = (_Float16)f;
    }
    ((half8*)wsw)[tile * 64 + lane] = v;
}

__global__ void k_bias(const float* __restrict__ b_ih,
                       const float* __restrict__ b_hh,
                       float* __restrict__ bias) {
    int id = blockIdx.x * 256 + threadIdx.x;   // 1024
    int nt = id >> 4, n = id & 15;
    int J = nt >> 2, g = nt & 3;
    int n_orig = g * 256 + J * 16 + n;
    bias[id] = b_ih[n_orig] + b_hh[n_orig];
}

__global__ void k_swz_fc(const float* __restrict__ w, _Float16* __restrict__ dst,
                         int ktiles, int K) {
    int tile = blockIdx.x;
    int nt = tile / ktiles, kt = tile - nt * ktiles;
    int lane = threadIdx.x;
    int n_in = lane & 15, kg = lane >> 4;
    int n_orig = nt * 16 + n_in;
    half8 v;
#pragma unroll
    for (int e = 0; e < 8; ++e) {
        int k = kt * 32 + kg * 8 + e;
        v[e] = (_Float16)w[n_orig * K + k];
    }
    ((half8*)dst)[tile * 64 + lane] = v;
}

// ---------------- recurrent LSTM v6: 128 WGs = 32 bb x 4 N-quarters --------
// R3-R5 lesson: 36-frag/wave (144 VGPR) weight sets get SPILLED by the
// allocator at the 256-reg budget (VGPR_Count stuck at 112, ~2.2us/step L2
// restream). v6 halves per-wave footprint: wave owns 1 J-block x 2 gates =
// 18 frags = 72 VGPRs; demand ~160 << 256 -> natural residency.
// Cost: gate halves exchanged via LDS; cross-WG sync degree 4 (counter).
__global__ __launch_bounds__(512, 1) void k_lstm6(
    const float* __restrict__ x, const _Float16* __restrict__ wsw,
    const float* __restrict__ bias, unsigned* __restrict__ hh32,
    unsigned* __restrict__ cnt) {
    __shared__ _Float16 h_lds[16][LDS_K];   // [m][k]: h(0..255) | x(256..271) | 0(272..287)
    __shared__ float glds[4][16][68];       // [gate][m][j_local 0..63], pad 68

    const int tid = threadIdx.x;
    const int wave = tid >> 6, lane = tid & 63;
    const int n_in = lane & 15, quad = lane >> 4;
    const int bb = blockIdx.x >> 2, ng = blockIdx.x & 3;
    const int b0 = bb * 16;
    const int Jl = wave & 3;               // local J-block 0..3
    const int gp = wave >> 2;              // gate pair: 0 -> (i,f), 1 -> (g,o)
    const int J = ng * 4 + Jl;             // global J-block 0..15

    // ---- load + pin 18 B-fragments (2 gates x 9 kt) + 2 biases ----
    half8 wpin[2][KTILES];
    float bs[2];
#pragma unroll
    for (int gg = 0; gg < 2; ++gg) {
        const int nt = J * 4 + gp * 2 + gg;
        bs[gg] = bias[nt * 16 + n_in];
#pragma unroll
        for (int kt = 0; kt < KTILES; ++kt)
            wpin[gg][kt] = ((const half8*)wsw)[(nt * KTILES + kt) * 64 + lane];
    }
#pragma unroll
    for (int gg = 0; gg < 2; ++gg)
#pragma unroll
        for (int kt = 0; kt < KTILES; ++kt) {
            floatx4 tmp = __builtin_bit_cast(floatx4, wpin[gg][kt]);
            asm volatile("" : "+v"(tmp));    // anchor (holds now that demand << budget)
            wpin[gg][kt] = __builtin_bit_cast(half8, tmp);
        }

    // zero h0 + pad, stage x_0
    for (int i = tid; i < 16 * LDS_K; i += 512)
        ((_Float16*)h_lds)[i] = (_Float16)0.0f;
    __syncthreads();
    if (tid < 256) {
        int m = tid >> 4, f = tid & 15;
        h_lds[m][Hsz + f] = (_Float16)x[((b0 + m) * Tsz + 0) * Fsz + f];
    }
    __syncthreads();

    // cell ownership: thread -> (m = tid>>5, j_local = 2*(tid&31)+e)
    const int cm = tid >> 5, cj = tid & 31;
    float c_st[2] = {0.f, 0.f};

    for (int t = 0; t < Tsz; ++t) {
        // ---- A-frags from LDS, MFMA with pinned weights ----
        half8 afr[KTILES];
#pragma unroll
        for (int kt = 0; kt < KTILES; ++kt)
            afr[kt] = *(const half8*)&h_lds[n_in][kt * 32 + quad * 8];

        floatx4 acc[2] = {(floatx4){0.f,0.f,0.f,0.f}, (floatx4){0.f,0.f,0.f,0.f}};
#pragma unroll
        for (int gg = 0; gg < 2; ++gg)
#pragma unroll
            for (int kt = 0; kt < KTILES; ++kt)
                acc[gg] = __builtin_amdgcn_mfma_f32_16x16x32_f16(afr[kt], wpin[gg][kt], acc[gg], 0, 0, 0);

        // ---- stage gate pre-activations to LDS ----
#pragma unroll
        for (int gg = 0; gg < 2; ++gg)
#pragma unroll
            for (int r = 0; r < 4; ++r)
                glds[gp * 2 + gg][quad * 4 + r][Jl * 16 + n_in] = acc[gg][r] + bs[gg];
        __syncthreads();   // G1: gates complete; afr reads also done -> h_lds writable

        // ---- cell update: thread owns (cm, j_local = 2cj, 2cj+1) ----
        union { _Float16 f[2]; unsigned u; } pk;
#pragma unroll
        for (int e = 0; e < 2; ++e) {
            int jl = 2 * cj + e;
            float ig = glds[0][cm][jl];
            float fg = glds[1][cm][jl];
            float gg_ = glds[2][cm][jl];
            float og = glds[3][cm][jl];
            float si = 1.0f / (1.0f + __expf(-ig));
            float sf = 1.0f / (1.0f + __expf(-fg));
            float tg = 1.0f - 2.0f / (__expf(2.0f * gg_) + 1.0f);
            float so = 1.0f / (1.0f + __expf(-og));
            float c = sf * c_st[e] + si * tg;
            c_st[e] = c;
            float th = 1.0f - 2.0f / (__expf(2.0f * c) + 1.0f);
            pk.f[e] = (_Float16)(so * th);
        }
        // own quarter of h_{t+1} straight into LDS (safe: reads done at G1)
        *(unsigned*)&h_lds[cm][ng * 64 + 2 * cj] = pk.u;
        // publish own quarter to hh (LLC, relaxed agent)
        __hip_atomic_store(hh32 + ((size_t)(b0 + cm) * Tsz + t) * 128 + ng * 32 + cj,
                           pk.u, __ATOMIC_RELAXED, __HIP_MEMORY_SCOPE_AGENT);

        // prefetch x_{t+1} while stores drain
        float xr = 0.0f;
        if (t + 1 < Tsz && tid < 256)
            xr = x[((b0 + (tid >> 4)) * Tsz + (t + 1)) * Fsz + (tid & 15)];

        __syncthreads();   // G2: vmcnt drained -> all WG stores at LLC

        if (t + 1 < Tsz) {
            if (tid == 0) {
                __hip_atomic_fetch_add(&cnt[t * 32 + bb], 1u,
                                       __ATOMIC_RELAXED, __HIP_MEMORY_SCOPE_AGENT);
                while (__hip_atomic_load(&cnt[t * 32 + bb], __ATOMIC_RELAXED,
                                         __HIP_MEMORY_SCOPE_AGENT) < 4u)
                    ;
            }
            __syncthreads();   // G3: all 4 quarters globally visible

            // gather 3 partner quarters (6 KB) into LDS; stage x_{t+1}
            {
                int m = tid >> 5, col = tid & 31;
                size_t base = ((size_t)(b0 + m) * Tsz + t) * 128;
#pragma unroll
                for (int qq = 1; qq < 4; ++qq) {
                    int pq = (ng + qq) & 3;
                    unsigned v = __hip_atomic_load(hh32 + base + pq * 32 + col,
                                                   __ATOMIC_RELAXED,
                                                   __HIP_MEMORY_SCOPE_AGENT);
                    *(unsigned*)&h_lds[m][pq * 64 + 2 * col] = v;
                }
                if (tid < 256)
                    h_lds[tid >> 4][Hsz + (tid & 15)] = (_Float16)xr;
            }
            __syncthreads();   // G4: full h_{t+1} + x_{t+1} staged
        }
    }
}

// ---------------- MLP head: 64 tokens/WG (4 waves x 16), MFMA f16 ----------
__global__ __launch_bounds__(256) void k_mlp(
    const _Float16* __restrict__ hh, const _Float16* __restrict__ w1f,
    const _Float16* __restrict__ w2f, const float* __restrict__ b1,
    const float* __restrict__ b2, const float* __restrict__ w3,
    const float* __restrict__ b3, float* __restrict__ out) {
    __shared__ _Float16 st1[4][16][136];
    __shared__ _Float16 st2[4][16][72];

    const int tid = threadIdx.x;
    const int wave = tid >> 6, lane = tid & 63;
    const int n_in = lane & 15, quad = lane >> 4;
    const int tok0 = blockIdx.x * 64 + wave * 16;

    half8 afr[8];
#pragma unroll
    for (int kt = 0; kt < 8; ++kt)
        afr[kt] = *(const half8*)&hh[(size_t)(tok0 + n_in) * 256 + kt * 32 + quad * 8];
    const half8* w1 = (const half8*)w1f;
#pragma unroll
    for (int nt = 0; nt < 8; ++nt) {
        floatx4 a = (floatx4){0.f, 0.f, 0.f, 0.f};
#pragma unroll
        for (int kt = 0; kt < 8; ++kt)
            a = __builtin_amdgcn_mfma_f32_16x16x32_f16(afr[kt], w1[(nt * 8 + kt) * 64 + lane], a, 0, 0, 0);
        float bb = b1[nt * 16 + n_in];
#pragma unroll
        for (int r = 0; r < 4; ++r) {
            float v = a[r] + bb;
            st1[wave][quad * 4 + r][nt * 16 + n_in] = (_Float16)(v > 0.f ? v : 0.f);
        }
    }
    __syncthreads();

    half8 a2[4];
#pragma unroll
    for (int kt = 0; kt < 4; ++kt)
        a2[kt] = *(const half8*)&st1[wave][n_in][kt * 32 + quad * 8];
    const half8* w2 = (const half8*)w2f;
#pragma unroll
    for (int nt = 0; nt < 4; ++nt) {
        floatx4 a = (floatx4){0.f, 0.f, 0.f, 0.f};
#pragma unroll
        for (int kt = 0; kt < 4; ++kt)
            a = __builtin_amdgcn_mfma_f32_16x16x32_f16(a2[kt], w2[(nt * 4 + kt) * 64 + lane], a, 0, 0, 0);
        float bb = b2[nt * 16 + n_in];
#pragma unroll
        for (int r = 0; r < 4; ++r) {
            float v = a[r] + bb;
            st2[wave][quad * 4 + r][nt * 16 + n_in] = (_Float16)(v > 0.f ? v : 0.f);
        }
    }
    __syncthreads();

    float p = 0.0f;
#pragma unroll
    for (int e = 0; e < 16; ++e)
        p += (float)st2[wave][n_in][quad * 16 + e] * w3[quad * 16 + e];
    p += __shfl_down(p, 32);
    p += __shfl_down(p, 16);
    if (quad == 0) out[tok0 + n_in] = p + b3[0];
}

extern "C" void kernel_launch(void* const* d_in, const int* in_sizes, int n_in,
                              void* d_out, int out_size, void* d_ws, size_t ws_size,
                              hipStream_t stream) {
    const float* x     = (const float*)d_in[0];
    const float* w_ih  = (const float*)d_in[1];
    const float* w_hh  = (const float*)d_in[2];
    const float* b_ih  = (const float*)d_in[3];
    const float* b_hh  = (const float*)d_in[4];
    const float* fc1_w = (const float*)d_in[5];
    const float* fc1_b = (const float*)d_in[6];
    const float* fc2_w = (const float*)d_in[7];
    const float* fc2_b = (const float*)d_in[8];
    const float* fc3_w = (const float*)d_in[9];
    const float* fc3_b = (const float*)d_in[10];

    char* ws = (char*)d_ws;
    _Float16* wsw  = (_Float16*)(ws + WSW_OFF);
    float*    bias = (float*)(ws + BIAS_OFF);
    _Float16* w1f  = (_Float16*)(ws + FC1_OFF);
    _Float16* w2f  = (_Float16*)(ws + FC2_OFF);
    _Float16* hhist= (_Float16*)(ws + HH_OFF);
    unsigned* cnt  = (unsigned*)(ws + CNT_OFF);

    hipMemsetAsync(cnt, 0, Tsz * 32 * sizeof(unsigned), stream);
    k_swz_whh<<<576, 64, 0, stream>>>(w_hh, w_ih, wsw);
    k_bias<<<4, 256, 0, stream>>>(b_ih, b_hh, bias);
    k_swz_fc<<<64, 64, 0, stream>>>(fc1_w, w1f, 8, 256);
    k_swz_fc<<<16, 64, 0, stream>>>(fc2_w, w2f, 4, 128);
    k_lstm6<<<128, 512, 0, stream>>>(x, wsw, bias, (unsigned*)hhist, cnt);
    k_mlp<<<Bsz * Tsz / 64, 256, 0, stream>>>(hhist, w1f, w2f, fc1_b, fc2_b,
                                              fc3_w, fc3_b, (float*)d_out);
}